// Round 4
// baseline (146.930 us; speedup 1.0000x reference)
//
#include <hip/hip_runtime.h>

// out[b,o] = sum_i silu(x)*BW + ((xs^2-1)*exp(-xs^2/2))*WW + bias,  xs=(x-T)/S
// Per-(o,i) precompute: a = C2/s^2, tn = -t, q = w * 2^C2 / C2  (C2=-0.5*log2 e)
// Per (b,o,i):  d = x+tn;  p = a*d^2 - C2  (= C2*xs^2 - C2, p in [-61, 0.722])
//               term = q * p * 2^p
// 2^p via magic-add split + deg-4 Taylor poly (rel err ~6e-5), exponent
// reinserted with v_lshl_add_u32 (bits<<23 + 0x3F800000).
// All v2f fp ops FORCED to v_pk_*_f32 via inline asm — round 3 showed the
// compiler scalarizes the whole loop when int bit-ops mix into the SLP chain
// (69 cyc/pair scalar vs 39 packed). Target: 34 issue-cyc/pair.

constexpr int IN_F  = 512;
constexpr int OUT_F = 512;
constexpr int BATCH = 1024;
constexpr int BT = 64, OT = 64;     // block tile
constexpr int KS = 8;               // k-split -> 16x8x8 = 1024 blocks, 4/CU
constexpr int KR = IN_F / KS;       // 64
constexpr int IT = 16;              // k chunk in LDS
constexpr int PITCH = IT + 4;       // 16B-aligned rows, worst 2-way banks (free)
constexpr int NCH = KR / IT;        // 4
constexpr int BO  = BATCH * OUT_F;  // 524288

#define LOG2E 1.44269504088897f
#define C2f   (-0.72134752044448f)
#define NC2f  ( 0.72134752044448f)
#define RQf   (-0.84083003f)          /* 2^C2 / C2 */
#define MAGICf 12582912.0f            /* 1.5 * 2^23 */

typedef float v2f __attribute__((ext_vector_type(2)));

__device__ __forceinline__ float fexp2(float v) { return __builtin_amdgcn_exp2f(v); }
__device__ __forceinline__ float frcp(float v)  { return __builtin_amdgcn_rcpf(v); }
__device__ __forceinline__ float fsilu(float v) {
  return v * frcp(1.f + fexp2(v * -LOG2E));
}

// ---- forced-packed fp32 ops (VOP3P) ----
__device__ __forceinline__ v2f pk_fma(v2f a, v2f b, v2f c) {
  v2f d;
  asm("v_pk_fma_f32 %0, %1, %2, %3" : "=v"(d) : "v"(a), "v"(b), "v"(c));
  return d;
}
__device__ __forceinline__ void pk_fma_acc(v2f& acc, v2f a, v2f b) {
  asm("v_pk_fma_f32 %0, %1, %2, %0" : "+v"(acc) : "v"(a), "v"(b));
}
__device__ __forceinline__ v2f pk_mul(v2f a, v2f b) {
  v2f d;
  asm("v_pk_mul_f32 %0, %1, %2" : "=v"(d) : "v"(a), "v"(b));
  return d;
}
__device__ __forceinline__ v2f pk_add(v2f a, v2f b) {
  v2f d;
  asm("v_pk_add_f32 %0, %1, %2" : "=v"(d) : "v"(a), "v"(b));
  return d;
}
// (bits(t) << 23) + bits(base);  base=1.0f supplies 0x3F800000
__device__ __forceinline__ float lshl23_add(float t, float base) {
  float d;
  asm("v_lshl_add_u32 %0, %1, 23, %2" : "=v"(d) : "v"(t), "v"(base));
  return d;
}

__global__ __launch_bounds__(256, 4)
void wkan_main(const float* __restrict__ x, const float* __restrict__ basew,
               const float* __restrict__ wavew, const float* __restrict__ scale,
               const float* __restrict__ transl, const float* __restrict__ bias,
               float* __restrict__ partial, float* __restrict__ out, int use_ws)
{
  __shared__ float lx [BT * PITCH];
  __shared__ float lsx[BT * PITCH];
  __shared__ float la [OT * PITCH];   // a = C2/s^2
  __shared__ float lt [OT * PITCH];   // -t
  __shared__ float lq [OT * PITCH];   // q = w*RQf
  __shared__ float lb [OT * PITCH];   // basew

  const int tid = threadIdx.x;
  const int b0 = blockIdx.x * BT;
  const int o0 = blockIdx.y * OT;
  const int ks = blockIdx.z;
  const int k0 = ks * KR;

  const int srow = tid >> 2;
  const int sc4  = (tid & 3) * 4;
  const int lofs = srow * PITCH + sc4;

  const int to = tid & 15;
  const int tb = tid >> 4;

  const v2f NC2v  = {NC2f, NC2f};
  const v2f MAGv  = {MAGICf, MAGICf};
  const v2f NMAGv = {-MAGICf, -MAGICf};
  const v2f NONEv = {-1.f, -1.f};
  const v2f P4 = {0.0096181291f, 0.0096181291f};
  const v2f P3 = {0.0555041087f, 0.0555041087f};
  const v2f P2 = {0.2402265070f, 0.2402265070f};
  const v2f P1 = {0.6931471806f, 0.6931471806f};
  const v2f P0 = {1.0f, 1.0f};
  const float ONEF = 1.0f;            // bits 0x3F800000

  v2f acc[4][4];
#pragma unroll
  for (int r = 0; r < 4; ++r)
#pragma unroll
    for (int c = 0; c < 4; ++c) acc[r][c] = (v2f){0.f, 0.f};

  for (int kc = 0; kc < NCH; ++kc) {
    const int g = k0 + kc * IT + sc4;
    __syncthreads();
    // ---------- stage chunk ----------
    {
      float4 xv = *(const float4*)(x + (size_t)(b0 + srow) * IN_F + g);
      float4 sx;
      sx.x = fsilu(xv.x); sx.y = fsilu(xv.y); sx.z = fsilu(xv.z); sx.w = fsilu(xv.w);
      *(float4*)(lx  + lofs) = xv;
      *(float4*)(lsx + lofs) = sx;

      float4 sv = *(const float4*)(scale  + (size_t)(o0 + srow) * IN_F + g);
      float4 av;
      av.x = C2f * frcp(sv.x * sv.x);
      av.y = C2f * frcp(sv.y * sv.y);
      av.z = C2f * frcp(sv.z * sv.z);
      av.w = C2f * frcp(sv.w * sv.w);
      *(float4*)(la + lofs) = av;

      float4 tv = *(const float4*)(transl + (size_t)(o0 + srow) * IN_F + g);
      float4 tn; tn.x = -tv.x; tn.y = -tv.y; tn.z = -tv.z; tn.w = -tv.w;
      *(float4*)(lt + lofs) = tn;

      float4 wv = *(const float4*)(wavew + (size_t)(o0 + srow) * IN_F + g);
      float4 qv;
      qv.x = wv.x * RQf; qv.y = wv.y * RQf; qv.z = wv.z * RQf; qv.w = wv.w * RQf;
      *(float4*)(lq + lofs) = qv;

      float4 bv = *(const float4*)(basew + (size_t)(o0 + srow) * IN_F + g);
      *(float4*)(lb + lofs) = bv;
    }
    __syncthreads();

    // ---------- compute: 4x4 outputs/thread ----------
    for (int ii = 0; ii < IT; ii += 4) {
      float4 xr[4], sr[4];
#pragma unroll
      for (int r = 0; r < 4; ++r) {
        const int row = (tb + 16 * r) * PITCH + ii;
        xr[r] = *(const float4*)(lx + row);
        sr[r] = *(const float4*)(lsx + row);
      }
#pragma unroll
      for (int c = 0; c < 4; ++c) {
        const int orow = (to + 16 * c) * PITCH + ii;
        float4 A = *(const float4*)(la + orow);
        float4 T = *(const float4*)(lt + orow);   // -t
        float4 Q = *(const float4*)(lq + orow);
        float4 B = *(const float4*)(lb + orow);
        v2f Al = {A.x, A.y}, Ah = {A.z, A.w};
        v2f Tl = {T.x, T.y}, Th = {T.z, T.w};
        v2f Ql = {Q.x, Q.y}, Qh = {Q.z, Q.w};
        v2f Bl = {B.x, B.y}, Bh = {B.z, B.w};
#pragma unroll
        for (int r = 0; r < 4; ++r) {
          v2f xl = {xr[r].x, xr[r].y}, xh = {xr[r].z, xr[r].w};
          v2f sl = {sr[r].x, sr[r].y}, sh = {sr[r].z, sr[r].w};
#pragma unroll
          for (int h = 0; h < 2; ++h) {
            v2f X  = h ? xh : xl, S  = h ? sh : sl;
            v2f Aa = h ? Ah : Al, Tt = h ? Th : Tl;
            v2f Qq = h ? Qh : Ql, Bb = h ? Bh : Bl;
            v2f dd = pk_add(X, Tt);          // x - t
            v2f ad = pk_mul(Aa, dd);
            v2f p  = pk_fma(ad, dd, NC2v);   // C2*xs^2 - C2
            v2f tt = pk_add(p, MAGv);        // magic round
            v2f nf = pk_add(tt, NMAGv);      // round(p)
            v2f f  = pk_fma(nf, NONEv, p);   // frac in [-0.5,0.5]
            v2f pl = pk_fma(P4, f, P3);
            pl = pk_fma(pl, f, P2);
            pl = pk_fma(pl, f, P1);
            pl = pk_fma(pl, f, P0);          // 2^f
            v2f pq = pk_mul(p, Qq);
            v2f pe = pk_mul(pq, pl);
            float s0 = lshl23_add(tt.x, ONEF);   // 2^round(p)
            float s1 = lshl23_add(tt.y, ONEF);
            acc[r][c].x = fmaf(pe.x, s0, acc[r][c].x);
            acc[r][c].y = fmaf(pe.y, s1, acc[r][c].y);
            pk_fma_acc(acc[r][c], S, Bb);    // base branch
          }
        }
      }
    }
  }

  // ---------- epilogue ----------
#pragma unroll
  for (int r = 0; r < 4; ++r) {
    const int br = b0 + tb + 16 * r;
#pragma unroll
    for (int c = 0; c < 4; ++c) {
      const int oc = o0 + to + 16 * c;
      float res = acc[r][c].x + acc[r][c].y;
      if (use_ws) {
        partial[(size_t)ks * BO + (size_t)br * OUT_F + oc] = res;
      } else {
        if (ks == 0) res += bias[oc];
        atomicAdd(out + (size_t)br * OUT_F + oc, res);
      }
    }
  }
}

__global__ __launch_bounds__(256)
void wkan_reduce(const float* __restrict__ partial, const float* __restrict__ bias,
                 float* __restrict__ out)
{
  const int i4 = (blockIdx.x * 256 + threadIdx.x) * 4;
  float4 r = *(const float4*)(bias + (i4 & (OUT_F - 1)));
#pragma unroll
  for (int k = 0; k < KS; ++k) {
    float4 a = *(const float4*)(partial + (size_t)k * BO + i4);
    r.x += a.x; r.y += a.y; r.z += a.z; r.w += a.w;
  }
  *(float4*)(out + i4) = r;
}

extern "C" void kernel_launch(void* const* d_in, const int* in_sizes, int n_in,
                              void* d_out, int out_size, void* d_ws, size_t ws_size,
                              hipStream_t stream) {
  const float* x  = (const float*)d_in[0];
  const float* bw = (const float*)d_in[1];
  const float* ww = (const float*)d_in[2];
  const float* sc = (const float*)d_in[3];
  const float* tr = (const float*)d_in[4];
  const float* bi = (const float*)d_in[5];
  float* out = (float*)d_out;

  const int use_ws = ws_size >= (size_t)KS * BO * sizeof(float) ? 1 : 0;
  if (!use_ws) {
    hipMemsetAsync(d_out, 0, (size_t)out_size * sizeof(float), stream);
  }
  dim3 grid(BATCH / BT, OUT_F / OT, KS);  // 16 x 8 x 8 = 1024 blocks
  wkan_main<<<grid, dim3(256), 0, stream>>>(x, bw, ww, sc, tr, bi,
                                            (float*)d_ws, out, use_ws);
  if (use_ws) {
    wkan_reduce<<<dim3(BO / 1024), dim3(256), 0, stream>>>((const float*)d_ws, bi, out);
  }
}

// Round 6
// 113.421 us; speedup vs baseline: 1.2954x; 1.2954x over previous
//
#include <hip/hip_runtime.h>

// out[b,o] = sum_i silu(x)*BW + ((xs^2-1)*exp(-xs^2/2))*WW + bias,  xs=(x-T)/S
// ROUND 6 = round-2 kernel (passed, 59.4us, packed-issue-verified) with ONE
// change: KS 4->8 (grid 512->1024 blocks = 4 blocks/CU) to lift occupancy.
// Round 5's triple-change kernel (bf16 pack + 128-tile + PITCH=18) failed
// correctness; reverted wholesale per one-change discipline.
//
// Per-(o,i) precompute at staging:
//   a2 = C2/s^2, m1 = -2*a2*t, m2' = a2*t^2 - C2, q = w * 2^C2 / C2
// with C2 = -0.5*log2(e).  Then per (b,o,i):
//   p = a2*x^2 + m1*x + m2'          (= C2*xs^2 - C2)
//   contribution = p * q * 2^p       (identity: (xs^2-1)*w*e^{-xs^2/2})
// Inner: 2 pk_fma + 1 pk_mul + 2 exp2 + 2 pk_fma acc per k-pair (hw v_exp).

constexpr int IN_F  = 512;
constexpr int OUT_F = 512;
constexpr int BATCH = 1024;
constexpr int BT = 64, OT = 64;     // block tile
constexpr int KS = 8;               // k-split -> grid 16x8x8 = 1024 blocks
constexpr int KR = IN_F / KS;       // 64 k per block
constexpr int IT = 16;              // k chunk in LDS
constexpr int PITCH = IT + 4;       // 16B-aligned rows, worst 2-way banks (free)
constexpr int NCH = KR / IT;        // 4 chunks
constexpr int BO  = BATCH * OUT_F;  // 524288

#define LOG2E 1.44269504088897f
#define C2f   (-0.72134752044448f)
#define NC2f  ( 0.72134752044448f)
#define RQf   (-0.84083003f)   /* 2^C2 / C2 = e^{-1/2}/C2 */

typedef float v2f __attribute__((ext_vector_type(2)));

__device__ __forceinline__ float fexp2(float v) { return __builtin_amdgcn_exp2f(v); }
__device__ __forceinline__ float frcp(float v)  { return __builtin_amdgcn_rcpf(v); }
__device__ __forceinline__ v2f pkfma(v2f a, v2f b, v2f c) {
  return __builtin_elementwise_fma(a, b, c);
}
__device__ __forceinline__ float fsilu(float v) {
  return v * frcp(1.f + fexp2(v * -LOG2E));
}

__global__ __launch_bounds__(256, 4)
void wkan_main(const float* __restrict__ x, const float* __restrict__ basew,
               const float* __restrict__ wavew, const float* __restrict__ scale,
               const float* __restrict__ transl, const float* __restrict__ bias,
               float* __restrict__ partial, float* __restrict__ out, int use_ws)
{
  __shared__ float lx [BT * PITCH];
  __shared__ float lsx[BT * PITCH];
  __shared__ float la [OT * PITCH];
  __shared__ float lm [OT * PITCH];
  __shared__ float ln [OT * PITCH];
  __shared__ float lq [OT * PITCH];
  __shared__ float lb [OT * PITCH];

  const int tid = threadIdx.x;
  const int b0 = blockIdx.x * BT;
  const int o0 = blockIdx.y * OT;
  const int ks = blockIdx.z;
  const int k0 = ks * KR;

  const int srow = tid >> 2;        // 0..63 staging row
  const int sc4  = (tid & 3) * 4;   // 0,4,8,12
  const int lofs = srow * PITCH + sc4;

  const int to = tid & 15;          // output col group
  const int tb = tid >> 4;          // output row group

  v2f zz; zz.x = 0.f; zz.y = 0.f;
  v2f acc[4][4];
#pragma unroll
  for (int r = 0; r < 4; ++r)
#pragma unroll
    for (int c = 0; c < 4; ++c) acc[r][c] = zz;

  for (int kc = 0; kc < NCH; ++kc) {
    const int g = k0 + kc * IT + sc4;
    __syncthreads();
    // ---------- stage chunk ----------
    {
      float4 xv = *(const float4*)(x + (size_t)(b0 + srow) * IN_F + g);
      float4 sx;
      sx.x = fsilu(xv.x); sx.y = fsilu(xv.y); sx.z = fsilu(xv.z); sx.w = fsilu(xv.w);
      *(float4*)(lx  + lofs) = xv;
      *(float4*)(lsx + lofs) = sx;

      float4 sv = *(const float4*)(scale  + (size_t)(o0 + srow) * IN_F + g);
      float4 tv = *(const float4*)(transl + (size_t)(o0 + srow) * IN_F + g);
      float4 av, mv, nv;
      {
        float a2, a2t;
        a2 = C2f * frcp(sv.x * sv.x); a2t = a2 * tv.x;
        av.x = a2; mv.x = -2.f * a2t; nv.x = fmaf(a2t, tv.x, NC2f);
        a2 = C2f * frcp(sv.y * sv.y); a2t = a2 * tv.y;
        av.y = a2; mv.y = -2.f * a2t; nv.y = fmaf(a2t, tv.y, NC2f);
        a2 = C2f * frcp(sv.z * sv.z); a2t = a2 * tv.z;
        av.z = a2; mv.z = -2.f * a2t; nv.z = fmaf(a2t, tv.z, NC2f);
        a2 = C2f * frcp(sv.w * sv.w); a2t = a2 * tv.w;
        av.w = a2; mv.w = -2.f * a2t; nv.w = fmaf(a2t, tv.w, NC2f);
      }
      *(float4*)(la + lofs) = av;
      *(float4*)(lm + lofs) = mv;
      *(float4*)(ln + lofs) = nv;

      float4 wv = *(const float4*)(wavew + (size_t)(o0 + srow) * IN_F + g);
      float4 qv;
      qv.x = wv.x * RQf; qv.y = wv.y * RQf; qv.z = wv.z * RQf; qv.w = wv.w * RQf;
      *(float4*)(lq + lofs) = qv;

      float4 bv = *(const float4*)(basew + (size_t)(o0 + srow) * IN_F + g);
      *(float4*)(lb + lofs) = bv;
    }
    __syncthreads();

    // ---------- compute: 4x4 outputs/thread ----------
    for (int ii = 0; ii < IT; ii += 4) {
      float4 xr[4], sr[4], x2[4];
#pragma unroll
      for (int r = 0; r < 4; ++r) {
        const int row = (tb + 16 * r) * PITCH + ii;
        xr[r] = *(const float4*)(lx + row);
        sr[r] = *(const float4*)(lsx + row);
        x2[r].x = xr[r].x * xr[r].x;
        x2[r].y = xr[r].y * xr[r].y;
        x2[r].z = xr[r].z * xr[r].z;
        x2[r].w = xr[r].w * xr[r].w;
      }
#pragma unroll
      for (int c = 0; c < 4; ++c) {
        const int orow = (to + 16 * c) * PITCH + ii;
        float4 A = *(const float4*)(la + orow);
        float4 M = *(const float4*)(lm + orow);
        float4 N = *(const float4*)(ln + orow);
        float4 Q = *(const float4*)(lq + orow);
        float4 B = *(const float4*)(lb + orow);
        v2f Al = {A.x, A.y}, Ah = {A.z, A.w};
        v2f Ml = {M.x, M.y}, Mh = {M.z, M.w};
        v2f Nl = {N.x, N.y}, Nh = {N.z, N.w};
        v2f Ql = {Q.x, Q.y}, Qh = {Q.z, Q.w};
        v2f Bl = {B.x, B.y}, Bh = {B.z, B.w};
#pragma unroll
        for (int r = 0; r < 4; ++r) {
          v2f xl  = {xr[r].x, xr[r].y}, xh  = {xr[r].z, xr[r].w};
          v2f x2l = {x2[r].x, x2[r].y}, x2h = {x2[r].z, x2[r].w};
          v2f sl  = {sr[r].x, sr[r].y}, sh  = {sr[r].z, sr[r].w};
          v2f p, e, gg;
          p = pkfma(Al, x2l, pkfma(Ml, xl, Nl));
          e.x = fexp2(p.x); e.y = fexp2(p.y);
          gg = p * Ql;
          acc[r][c] = pkfma(gg, e, acc[r][c]);
          acc[r][c] = pkfma(sl, Bl, acc[r][c]);
          p = pkfma(Ah, x2h, pkfma(Mh, xh, Nh));
          e.x = fexp2(p.x); e.y = fexp2(p.y);
          gg = p * Qh;
          acc[r][c] = pkfma(gg, e, acc[r][c]);
          acc[r][c] = pkfma(sh, Bh, acc[r][c]);
        }
      }
    }
  }

  // ---------- epilogue ----------
#pragma unroll
  for (int r = 0; r < 4; ++r) {
    const int br = b0 + tb + 16 * r;
#pragma unroll
    for (int c = 0; c < 4; ++c) {
      const int oc = o0 + to + 16 * c;
      float res = acc[r][c].x + acc[r][c].y;
      if (use_ws) {
        partial[(size_t)ks * BO + (size_t)br * OUT_F + oc] = res;
      } else {
        if (ks == 0) res += bias[oc];
        atomicAdd(out + (size_t)br * OUT_F + oc, res);
      }
    }
  }
}

__global__ __launch_bounds__(256)
void wkan_reduce(const float* __restrict__ partial, const float* __restrict__ bias,
                 float* __restrict__ out)
{
  const int i4 = (blockIdx.x * 256 + threadIdx.x) * 4;
  float4 r = *(const float4*)(bias + (i4 & (OUT_F - 1)));
#pragma unroll
  for (int k = 0; k < KS; ++k) {
    float4 a = *(const float4*)(partial + (size_t)k * BO + i4);
    r.x += a.x; r.y += a.y; r.z += a.z; r.w += a.w;
  }
  *(float4*)(out + i4) = r;
}

extern "C" void kernel_launch(void* const* d_in, const int* in_sizes, int n_in,
                              void* d_out, int out_size, void* d_ws, size_t ws_size,
                              hipStream_t stream) {
  const float* x  = (const float*)d_in[0];
  const float* bw = (const float*)d_in[1];
  const float* ww = (const float*)d_in[2];
  const float* sc = (const float*)d_in[3];
  const float* tr = (const float*)d_in[4];
  const float* bi = (const float*)d_in[5];
  float* out = (float*)d_out;

  const int use_ws = ws_size >= (size_t)KS * BO * sizeof(float) ? 1 : 0;
  if (!use_ws) {
    hipMemsetAsync(d_out, 0, (size_t)out_size * sizeof(float), stream);
  }
  dim3 grid(BATCH / BT, OUT_F / OT, KS);  // 16 x 8 x 8 = 1024 blocks, 4/CU
  wkan_main<<<grid, dim3(256), 0, stream>>>(x, bw, ww, sc, tr, bi,
                                            (float*)d_ws, out, use_ws);
  if (use_ws) {
    wkan_reduce<<<dim3(BO / 1024), dim3(256), 0, stream>>>((const float*)d_ws, bi, out);
  }
}